// Round 2
// baseline (91.563 us; speedup 1.0000x reference)
//
#include <hip/hip_runtime.h>

#define NH 254
#define NSTEP 32
#define NB 256

constexpr float  FEPS = 1e-4f;
constexpr double DDT  = 1.0 / 60.0;
constexpr double DQV  = 200.0;
constexpr double DPQ  = 5.0;
constexpr double DQA  = 1.0;
constexpr double DEPS = 1e-4;

// ---------------------------------------------------------------------------
// K1: partial t = Lq^T Af. Block b covers rows [8b, 8b+8); thread k owns col k.
// Lower-triangular: row i contributes to col k only when i >= k.
// ---------------------------------------------------------------------------
__global__ __launch_bounds__(256) void k_phase1(const float* __restrict__ Lq,
                                                const float* __restrict__ Af,
                                                float* __restrict__ partial) {
    const int k  = threadIdx.x;
    const int b  = blockIdx.x;
    const int i0 = b * 8;
    const int iend = (i0 + 8 < NH) ? i0 + 8 : NH;
    float acc = 0.f;
    if (k < NH) {
        int ibeg = (k > i0) ? k : i0;
        for (int i = ibeg; i < iend; ++i)
            acc += Lq[i * NH + k] * Af[i];
    }
    partial[b * 256 + k] = acc;
}

// ---------------------------------------------------------------------------
// K2: blocks 0..31: g rows (g = Lq t + eps Af).  Block 32: scalar pipeline:
// c = ||t||^2 + eps||Af||^2, build Q_final (fp64), Gauss-Jordan solve for
// ualpha/ubeta, prefix-sum into output coefficients.
// ---------------------------------------------------------------------------
__global__ __launch_bounds__(256) void k_phase2(const float* __restrict__ Lq,
                                                const float* __restrict__ Af,
                                                const float* __restrict__ partial,
                                                float* __restrict__ g,
                                                float* __restrict__ coef) {
    __shared__ float t_sh[256];
    const int k = threadIdx.x;
    const int lane = k & 63;
    const int w = k >> 6;

    float tk = 0.f;
    #pragma unroll
    for (int b = 0; b < 32; ++b) tk += partial[b * 256 + k];
    t_sh[k] = tk;
    __syncthreads();

    if (blockIdx.x < 32) {
        // wave w handles rows i0 + 2w + {0,1}; i is wave-uniform.
        const int i0 = blockIdx.x * 8;
        for (int rr = 0; rr < 2; ++rr) {
            const int i = i0 + 2 * w + rr;
            if (i >= NH) break;
            float acc = 0.f;
            #pragma unroll
            for (int c4 = 0; c4 < 4; ++c4) {
                int kk = lane + 64 * c4;
                if (kk <= i) acc += Lq[i * NH + kk] * t_sh[kk];  // kk<=i implies kk<NH
            }
            #pragma unroll
            for (int off = 32; off; off >>= 1) acc += __shfl_xor(acc, off, 64);
            if (lane == 0) g[i] = acc + FEPS * Af[i];
        }
        return;
    }

    // ---- block 32: scalar pipeline in fp64 ----
    __shared__ double red[4];
    __shared__ double M[32][34];
    __shared__ double ua[32], ub[32];

    double v = 0.0;
    if (k < NH) {
        double td = (double)t_sh[k];
        double ad = (double)Af[k];
        v = td * td + DEPS * ad * ad;
    }
    #pragma unroll
    for (int off = 32; off; off >>= 1) v += __shfl_xor(v, off, 64);
    if (lane == 0) red[w] = v;
    __syncthreads();
    const double c = red[0] + red[1] + red[2] + red[3];

    // Q_final entries: 1024 entries over 256 threads
    for (int e = k; e < 1024; e += 256) {
        const int j1 = e >> 5, j2 = e & 31;
        const int m = (j1 > j2) ? j1 : j2;
        double s = 0.0;
        for (int kk = m; kk < 32; ++kk) {
            const double wk = (kk == 31) ? DPQ : 1.0;
            s += wk * ((double)(kk - j1) * (double)(kk - j2) * c + DQV);
        }
        M[j1][j2] = 2.0 * DDT * DDT * s + ((j1 == j2) ? (2.0 * DQA + DEPS) : 0.0);
    }
    // RHS: alpha (col 32), beta (col 33)
    if (k < 32) {
        const int j = k;
        double sa = 0.0, sb = 0.0;
        for (int kk = j; kk < 32; ++kk) {
            const double wk = (kk == 31) ? DPQ : 1.0;
            sa += wk * (double)(kk - j);
            sb += wk * ((double)(kk + 1) * (double)(kk - j) * c + DQV);
        }
        M[j][32] = 2.0 * DDT * sa;
        M[j][33] = 2.0 * DDT * sb;
    }
    __syncthreads();

    // Gauss-Jordan, no pivoting (SPD). Thread -> (row r, col-group cg).
    const int r  = k & 31;
    const int cg = k >> 5;   // 0..7
    for (int p = 0; p < 32; ++p) {
        const double f = M[r][p] / M[p][p];
        if (r != p) {
            for (int cc = cg; cc < 34; cc += 8)
                if (cc > p) M[r][cc] -= f * M[p][cc];
        }
        __syncthreads();
    }

    if (k < 32) {
        ua[k] = -M[k][32] / M[k][k];
        ub[k] = -M[k][33] / M[k][k];
    }
    __syncthreads();

    if (k < 32) {
        const int i = k;
        double ca = 0.0, cb = 0.0;
        for (int j = 0; j <= i; ++j) {
            const double wgt = (double)(i - j) + 0.5;
            ca += wgt * ua[j];
            cb += wgt * ub[j];
        }
        ca *= DDT * DDT;
        cb *= DDT * DDT;
        coef[i]      = (float)ca;                           // Calpha_i
        coef[32 + i] = (float)((double)(i + 1) * DDT + cb); // (i+1)dt + Cbeta_i
    }
}

// ---------------------------------------------------------------------------
// K3: one wave per batch row. s_b = x_b . g ; out[b,i] = p_b + v_b*vc_i + s_b*Ca_i
// ---------------------------------------------------------------------------
__global__ __launch_bounds__(64) void k_phase3(const float* __restrict__ x,
                                               const float* __restrict__ gp,
                                               const float* __restrict__ gv,
                                               const float* __restrict__ g,
                                               const float* __restrict__ coef,
                                               float* __restrict__ out) {
    const int b = blockIdx.x;
    const int lane = threadIdx.x;
    float acc = 0.f;
    #pragma unroll
    for (int c4 = 0; c4 < 4; ++c4) {
        const int kk = lane + 64 * c4;
        if (kk < NH) acc += x[b * NH + kk] * g[kk];
    }
    #pragma unroll
    for (int off = 32; off; off >>= 1) acc += __shfl_xor(acc, off, 64);
    if (lane < 32) {
        out[b * NSTEP + lane] = gp[b] + gv[b] * coef[32 + lane] + acc * coef[lane];
    }
}

extern "C" void kernel_launch(void* const* d_in, const int* in_sizes, int n_in,
                              void* d_out, int out_size, void* d_ws, size_t ws_size,
                              hipStream_t stream) {
    const float* x  = (const float*)d_in[0];   // [256,254]
    const float* gp = (const float*)d_in[1];   // [256]
    const float* gv = (const float*)d_in[2];   // [256]
    // d_in[3] (other_gripper_v) unused by the forward path
    const float* Af = (const float*)d_in[4];   // [254]
    const float* Lq = (const float*)d_in[5];   // [254,254]
    float* out = (float*)d_out;                // [256,32]

    float* ws      = (float*)d_ws;
    float* partial = ws;              // 32*256 floats
    float* g       = ws + 32 * 256;   // 256 floats
    float* coef    = g + 256;         // 64 floats

    k_phase1<<<32, 256, 0, stream>>>(Lq, Af, partial);
    k_phase2<<<33, 256, 0, stream>>>(Lq, Af, partial, g, coef);
    k_phase3<<<NB, 64, 0, stream>>>(x, gp, gv, g, coef, out);
}